// Round 1
// baseline (1319.630 us; speedup 1.0000x reference)
//
#include <hip/hip_runtime.h>
#include <stdint.h>

#define Bb 128
#define Nn 1024
#define Dd 512
#define Ss 64

constexpr float kScale = 0.044194173824159216f;  // 512^-0.5
constexpr float kEps = 1e-8f;

typedef __bf16 bf16x8 __attribute__((ext_vector_type(8)));
typedef float f32x4 __attribute__((ext_vector_type(4)));

__device__ inline unsigned short f2bf_rne(float x) {
  unsigned u = __builtin_bit_cast(unsigned, x);
  u += 0x7FFFu + ((u >> 16) & 1u);
  return (unsigned short)(u >> 16);
}
__device__ inline float bf2f(unsigned short h) {
  unsigned u = ((unsigned)h) << 16;
  return __builtin_bit_cast(float, u);
}

// async global->LDS, 16B per lane; lds dest must be wave-uniform base (lane*16 implicit)
__device__ inline void gl_lds16(const void* g, void* l) {
  typedef unsigned int u32;
  auto gp = (u32 __attribute__((address_space(1)))*)(unsigned long long)(uintptr_t)g;
  auto lp = (u32 __attribute__((address_space(3)))*)(unsigned int)(uintptr_t)l;
  __builtin_amdgcn_global_load_lds(gp, lp, 16, 0, 0);
}

// f32 -> bf16 hi/lo split (a ~= hi + lo, residual ~2^-16 rel)
__global__ void cast_split(const float* __restrict__ in,
                           unsigned short* __restrict__ hi,
                           unsigned short* __restrict__ lo,
                           int n4) {
  int i = blockIdx.x * blockDim.x + threadIdx.x;
  const int stride = gridDim.x * blockDim.x;
  for (; i < n4; i += stride) {
    const float4 v = ((const float4*)in)[i];
    ushort4 h, lw;
    h.x = f2bf_rne(v.x); lw.x = f2bf_rne(v.x - bf2f(h.x));
    h.y = f2bf_rne(v.y); lw.y = f2bf_rne(v.y - bf2f(h.y));
    h.z = f2bf_rne(v.z); lw.z = f2bf_rne(v.z - bf2f(h.z));
    h.w = f2bf_rne(v.w); lw.w = f2bf_rne(v.w - bf2f(h.w));
    ((ushort4*)hi)[i] = h;
    ((ushort4*)lo)[i] = lw;
  }
}

// C[M,512] = act(A[M,512] @ W[512,512]^T + bias), all operands bf16 hi/lo split.
// 128x128 tile, BK=32, 4 waves (2x2 of 64x64), 16x16x32 bf16 MFMA, 3 MFMAs/frag-pair.
template <int ACT>
__global__ __launch_bounds__(256) void gemm_split(
    const unsigned short* __restrict__ Ah, const unsigned short* __restrict__ Al,
    const unsigned short* __restrict__ Wh, const unsigned short* __restrict__ Wl,
    const float* __restrict__ bias,
    unsigned short* __restrict__ Ch, unsigned short* __restrict__ Cl) {
  constexpr int K = 512, NN = 512, BM = 128, BK = 32;
  __shared__ __align__(16) unsigned short lah[BM * BK];
  __shared__ __align__(16) unsigned short lal[BM * BK];
  __shared__ __align__(16) unsigned short lbh[BM * BK];
  __shared__ __align__(16) unsigned short lbl[BM * BK];
  const int t = threadIdx.x, l = t & 63, w = t >> 6;
  const int wr = w >> 1, wc = w & 1;
  const int br = blockIdx.x >> 2;  // 512/128 = 4 col tiles
  const int bc = blockIdx.x & 3;
  const long rowA0 = (long)br * BM;
  const int colB0 = bc * BM;

  f32x4 acc[4][4] = {};

  for (int k0 = 0; k0 < K; k0 += BK) {
#pragma unroll
    for (int q = 0; q < 2; q++) {
      const int c = q * 256 + t;
      const long ga = (rowA0 + (c >> 2)) * K + k0 + (c & 3) * 8;
      const long gb = (long)(colB0 + (c >> 2)) * K + k0 + (c & 3) * 8;
      const int lo = (q * 256 + w * 64) * 8;
      gl_lds16(Ah + ga, lah + lo);
      gl_lds16(Al + ga, lal + lo);
      gl_lds16(Wh + gb, lbh + lo);
      gl_lds16(Wl + gb, lbl + lo);
    }
    __syncthreads();
    bf16x8 ah[4], al[4], bh[4], bl[4];
#pragma unroll
    for (int m = 0; m < 4; m++) {
      const int off = (wr * 64 + m * 16 + (l & 15)) * BK + (l >> 4) * 8;
      ah[m] = *(const bf16x8*)(lah + off);
      al[m] = *(const bf16x8*)(lal + off);
    }
#pragma unroll
    for (int n = 0; n < 4; n++) {
      const int off = (wc * 64 + n * 16 + (l & 15)) * BK + (l >> 4) * 8;
      bh[n] = *(const bf16x8*)(lbh + off);
      bl[n] = *(const bf16x8*)(lbl + off);
    }
#pragma unroll
    for (int m = 0; m < 4; m++)
#pragma unroll
      for (int n = 0; n < 4; n++) {
        acc[m][n] = __builtin_amdgcn_mfma_f32_16x16x32_bf16(ah[m], bh[n], acc[m][n], 0, 0, 0);
        acc[m][n] = __builtin_amdgcn_mfma_f32_16x16x32_bf16(al[m], bh[n], acc[m][n], 0, 0, 0);
        acc[m][n] = __builtin_amdgcn_mfma_f32_16x16x32_bf16(ah[m], bl[n], acc[m][n], 0, 0, 0);
      }
    __syncthreads();
  }
#pragma unroll
  for (int m = 0; m < 4; m++) {
    const long row = rowA0 + wr * 64 + m * 16 + (l >> 4) * 4;
#pragma unroll
    for (int n = 0; n < 4; n++) {
      const int col = colB0 + wc * 64 + n * 16 + (l & 15);
      const float bv = bias[col];
#pragma unroll
      for (int r = 0; r < 4; r++) {
        float x = acc[m][n][r] + bv;
        if (ACT) x = fmaxf(x, 0.0f);
        const unsigned short h = f2bf_rne(x);
        const long idx = (row + r) * NN + col;
        Ch[idx] = h;
        Cl[idx] = f2bf_rne(x - bf2f(h));
      }
    }
  }
}

// dots[b,64,1024] = scale * slots[64,512] @ k[b,1024,512]^T  (split bf16 MFMA, f32 out)
__global__ __launch_bounds__(256) void gemm_dots_split(
    const unsigned short* __restrict__ Qh, const unsigned short* __restrict__ Ql,
    const unsigned short* __restrict__ Kh, const unsigned short* __restrict__ Kl,
    float* __restrict__ dots) {
  constexpr int K = 512, BM = 64, BN = 128, BK = 32;
  __shared__ __align__(16) unsigned short lah[BM * BK];
  __shared__ __align__(16) unsigned short lal[BM * BK];
  __shared__ __align__(16) unsigned short lbh[BN * BK];
  __shared__ __align__(16) unsigned short lbl[BN * BK];
  const int t = threadIdx.x, l = t & 63, w = t >> 6;
  const int b = blockIdx.x >> 3, bc = blockIdx.x & 7;
  const unsigned short* kh = Kh + (long)b * Nn * Dd;
  const unsigned short* kl = Kl + (long)b * Nn * Dd;
  f32x4 acc[4][2] = {};

  for (int k0 = 0; k0 < K; k0 += BK) {
    {
      const int c = t;
      const int ga = (c >> 2) * K + k0 + (c & 3) * 8;
      const int lo = (w * 64) * 8;
      gl_lds16(Qh + ga, lah + lo);
      gl_lds16(Ql + ga, lal + lo);
    }
#pragma unroll
    for (int q = 0; q < 2; q++) {
      const int c = q * 256 + t;
      const long gb = (long)(bc * BN + (c >> 2)) * K + k0 + (c & 3) * 8;
      const int lo = (q * 256 + w * 64) * 8;
      gl_lds16(kh + gb, lbh + lo);
      gl_lds16(kl + gb, lbl + lo);
    }
    __syncthreads();
    bf16x8 ah[4], al[4], bh[2], bl[2];
#pragma unroll
    for (int m = 0; m < 4; m++) {
      const int off = (m * 16 + (l & 15)) * BK + (l >> 4) * 8;
      ah[m] = *(const bf16x8*)(lah + off);
      al[m] = *(const bf16x8*)(lal + off);
    }
#pragma unroll
    for (int n = 0; n < 2; n++) {
      const int off = (w * 32 + n * 16 + (l & 15)) * BK + (l >> 4) * 8;
      bh[n] = *(const bf16x8*)(lbh + off);
      bl[n] = *(const bf16x8*)(lbl + off);
    }
#pragma unroll
    for (int m = 0; m < 4; m++)
#pragma unroll
      for (int n = 0; n < 2; n++) {
        acc[m][n] = __builtin_amdgcn_mfma_f32_16x16x32_bf16(ah[m], bh[n], acc[m][n], 0, 0, 0);
        acc[m][n] = __builtin_amdgcn_mfma_f32_16x16x32_bf16(al[m], bh[n], acc[m][n], 0, 0, 0);
        acc[m][n] = __builtin_amdgcn_mfma_f32_16x16x32_bf16(ah[m], bl[n], acc[m][n], 0, 0, 0);
      }
    __syncthreads();
  }
  float* dp = dots + (long)b * Ss * Nn;
#pragma unroll
  for (int m = 0; m < 4; m++) {
    const int row = m * 16 + (l >> 4) * 4;
#pragma unroll
    for (int n = 0; n < 2; n++) {
      const int col = bc * BN + w * 32 + n * 16 + (l & 15);
#pragma unroll
      for (int r = 0; r < 4; r++) dp[(long)(row + r) * Nn + col] = acc[m][n][r] * kScale;
    }
  }
}

// per-batch: s_j[b,i] = sum_j dots, s_all[b] = sum_ij dots
__global__ __launch_bounds__(256) void reduce_k(
    const float* __restrict__ dots, float* __restrict__ s_j, float* __restrict__ s_all) {
  const int b = blockIdx.x;
  const int t = threadIdx.x;
  const float* dp = dots + (long)b * Ss * Nn;
  const int i = t >> 2, q = t & 3;
  float s = 0.f;
  const float* rp = dp + i * Nn + q * 256;
  for (int j = 0; j < 256; j++) s += rp[j];
  __shared__ float part[256];
  __shared__ float rowsum[64];
  part[t] = s;
  __syncthreads();
  if (t < 64) {
    const float v = part[t * 4] + part[t * 4 + 1] + part[t * 4 + 2] + part[t * 4 + 3];
    rowsum[t] = v;
    s_j[b * 64 + t] = v;
  }
  __syncthreads();
  if (t == 0) {
    float tot = 0.f;
    for (int k = 0; k < 64; k++) tot += rowsum[k];
    s_all[b] = tot;
  }
}

// attn = sigmoid(dots * s_all/s_j) -> out; inv_r = 1/(rowsum(attn)+eps)
__global__ __launch_bounds__(256) void attn_k(
    const float* __restrict__ dots, const float* __restrict__ s_j,
    const float* __restrict__ s_all, float* __restrict__ attn_out,
    float* __restrict__ inv_r) {
  const int bi = blockIdx.x;
  const int b = bi >> 6;
  const int t = threadIdx.x;
  const float ratio = s_all[b] / s_j[bi];
  const float* dp = dots + (long)bi * Nn;
  float* ap = attn_out + (long)bi * Nn;
  float s = 0.f;
#pragma unroll
  for (int q = 0; q < 4; q++) {
    const int j = q * 256 + t;
    const float x = dp[j] * ratio;
    const float a = 1.f / (1.f + expf(-x));
    ap[j] = a;
    s += a;
  }
  __shared__ float red[256];
  red[t] = s;
  __syncthreads();
  for (int off = 128; off > 0; off >>= 1) {
    if (t < off) red[t] += red[t + off];
    __syncthreads();
  }
  if (t == 0) inv_r[bi] = 1.f / (red[0] + kEps);
}

// updates[b,i,d] = inv_r[b,i] * sum_j attn[b,i,j] * inputs[b,j,d]   (fp32, LDS-tiled)
__global__ __launch_bounds__(256) void updates_k(
    const float* __restrict__ attn, const float* __restrict__ inputs,
    const float* __restrict__ inv_r, float* __restrict__ out0) {
  const int b = blockIdx.x >> 2;
  const int dt = blockIdx.x & 3;
  const int t = threadIdx.x;
  __shared__ float att_lds[64 * 32];
  __shared__ float in_lds[32 * 128];
  const int c = (t & 63) * 2;
  const int g = t >> 6;
  float accx[16], accy[16];
#pragma unroll
  for (int i = 0; i < 16; i++) { accx[i] = 0.f; accy[i] = 0.f; }
  for (int j0 = 0; j0 < Nn; j0 += 32) {
    __syncthreads();
#pragma unroll
    for (int s2 = 0; s2 < 8; s2++) {
      const int e = s2 * 256 + t;
      att_lds[e] = attn[(long)(b * 64 + (e >> 5)) * Nn + j0 + (e & 31)];
    }
#pragma unroll
    for (int s2 = 0; s2 < 16; s2++) {
      const int e = s2 * 256 + t;
      in_lds[e] = inputs[(long)b * Nn * Dd + (long)(j0 + (e >> 7)) * Dd + dt * 128 + (e & 127)];
    }
    __syncthreads();
#pragma unroll 4
    for (int jj = 0; jj < 32; jj++) {
      const float ix = in_lds[jj * 128 + c];
      const float iy = in_lds[jj * 128 + c + 1];
#pragma unroll
      for (int ii = 0; ii < 16; ii++) {
        const float a = att_lds[(g * 16 + ii) * 32 + jj];
        accx[ii] += a * ix;
        accy[ii] += a * iy;
      }
    }
  }
#pragma unroll
  for (int ii = 0; ii < 16; ii++) {
    const int i = g * 16 + ii;
    const float ir = inv_r[b * 64 + i];
    const long o = (long)(b * 64 + i) * Dd + dt * 128 + c;
    out0[o] = accx[ii] * ir;
    out0[o + 1] = accy[ii] * ir;
  }
}

extern "C" void kernel_launch(void* const* d_in, const int* in_sizes, int n_in,
                              void* d_out, int out_size, void* d_ws, size_t ws_size,
                              hipStream_t stream) {
  (void)in_sizes; (void)n_in; (void)out_size; (void)ws_size;
  const float* inputs_pe = (const float*)d_in[0];
  const float* inputs = (const float*)d_in[1];
  const float* slots = (const float*)d_in[2];
  const float* W1 = (const float*)d_in[3];
  const float* b1 = (const float*)d_in[4];
  const float* W2 = (const float*)d_in[5];
  const float* b2 = (const float*)d_in[6];
  const float* W3 = (const float*)d_in[7];
  const float* b3 = (const float*)d_in[8];

  char* ws = (char*)d_ws;
  size_t off = 0;
  auto alloc = [&](size_t bytes) -> void* {
    void* p = ws + off;
    off += (bytes + 255) & ~(size_t)255;
    return p;
  };
  const size_t actB = (size_t)Bb * Nn * Dd * 2;  // 128 MB per bf16 activation buffer
  unsigned short* Ahi = (unsigned short*)alloc(actB);
  unsigned short* Alo = (unsigned short*)alloc(actB);
  unsigned short* Bhi = (unsigned short*)alloc(actB);
  unsigned short* Blo = (unsigned short*)alloc(actB);
  unsigned short* w1h = (unsigned short*)alloc(Dd * Dd * 2);
  unsigned short* w1l = (unsigned short*)alloc(Dd * Dd * 2);
  unsigned short* w2h = (unsigned short*)alloc(Dd * Dd * 2);
  unsigned short* w2l = (unsigned short*)alloc(Dd * Dd * 2);
  unsigned short* w3h = (unsigned short*)alloc(Dd * Dd * 2);
  unsigned short* w3l = (unsigned short*)alloc(Dd * Dd * 2);
  unsigned short* sh = (unsigned short*)alloc(Ss * Dd * 2);
  unsigned short* sl = (unsigned short*)alloc(Ss * Dd * 2);
  float* dotsb = (float*)alloc((size_t)Bb * Ss * Nn * 4);
  float* s_j = (float*)alloc(Bb * Ss * 4);
  float* s_all = (float*)alloc(Bb * 4);
  float* inv_r = (float*)alloc(Bb * Ss * 4);

  float* out_updates = (float*)d_out;
  float* out_attn = out_updates + (size_t)Bb * Ss * Dd;

  cast_split<<<4096, 256, 0, stream>>>(inputs_pe, Ahi, Alo, Bb * Nn * Dd / 4);
  cast_split<<<256, 256, 0, stream>>>(W1, w1h, w1l, Dd * Dd / 4);
  cast_split<<<256, 256, 0, stream>>>(W2, w2h, w2l, Dd * Dd / 4);
  cast_split<<<256, 256, 0, stream>>>(W3, w3h, w3l, Dd * Dd / 4);
  cast_split<<<32, 256, 0, stream>>>(slots, sh, sl, Ss * Dd / 4);

  gemm_split<1><<<4096, 256, 0, stream>>>(Ahi, Alo, w1h, w1l, b1, Bhi, Blo);
  gemm_split<1><<<4096, 256, 0, stream>>>(Bhi, Blo, w2h, w2l, b2, Ahi, Alo);
  gemm_split<0><<<4096, 256, 0, stream>>>(Ahi, Alo, w3h, w3l, b3, Bhi, Blo);

  gemm_dots_split<<<Bb * 8, 256, 0, stream>>>(sh, sl, Bhi, Blo, dotsb);
  reduce_k<<<Bb, 256, 0, stream>>>(dotsb, s_j, s_all);
  attn_k<<<Bb * Ss, 256, 0, stream>>>(dotsb, s_j, s_all, out_attn, inv_r);
  updates_k<<<Bb * 4, 256, 0, stream>>>(out_attn, inputs, inv_r, out_updates);
}

// Round 2
// 1205.889 us; speedup vs baseline: 1.0943x; 1.0943x over previous
//
#include <hip/hip_runtime.h>
#include <stdint.h>

#define Bb 128
#define Nn 1024
#define Dd 512
#define Ss 64

constexpr float kScale = 0.044194173824159216f;  // 512^-0.5
constexpr float kEps = 1e-8f;

typedef __bf16 bf16x8 __attribute__((ext_vector_type(8)));
typedef float f32x4 __attribute__((ext_vector_type(4)));

__device__ inline unsigned short f2bf_rne(float x) {
  unsigned u = __builtin_bit_cast(unsigned, x);
  u += 0x7FFFu + ((u >> 16) & 1u);
  return (unsigned short)(u >> 16);
}
__device__ inline float bf2f(unsigned short h) {
  unsigned u = ((unsigned)h) << 16;
  return __builtin_bit_cast(float, u);
}

// async global->LDS, 16B per lane; LDS dest must be wave-uniform base (HW adds lane*16)
__device__ inline void gl_lds16(const void* g, void* l) {
  typedef unsigned int u32;
  auto gp = (u32 __attribute__((address_space(1)))*)(unsigned long long)(uintptr_t)g;
  auto lp = (u32 __attribute__((address_space(3)))*)(unsigned int)(uintptr_t)l;
  __builtin_amdgcn_global_load_lds(gp, lp, 16, 0, 0);
}

// f32 -> bf16 hi/lo split (a ~= hi + lo, residual ~2^-16 rel)
__global__ void cast_split(const float* __restrict__ in,
                           unsigned short* __restrict__ hi,
                           unsigned short* __restrict__ lo,
                           int n4) {
  int i = blockIdx.x * blockDim.x + threadIdx.x;
  const int stride = gridDim.x * blockDim.x;
  for (; i < n4; i += stride) {
    const float4 v = ((const float4*)in)[i];
    ushort4 h, lw;
    h.x = f2bf_rne(v.x); lw.x = f2bf_rne(v.x - bf2f(h.x));
    h.y = f2bf_rne(v.y); lw.y = f2bf_rne(v.y - bf2f(h.y));
    h.z = f2bf_rne(v.z); lw.z = f2bf_rne(v.z - bf2f(h.z));
    h.w = f2bf_rne(v.w); lw.w = f2bf_rne(v.w - bf2f(h.w));
    ((ushort4*)hi)[i] = h;
    ((ushort4*)lo)[i] = lw;
  }
}

// C[M,512] = act(A[M,512] @ W[512,512]^T + bias), split bf16 (3 MFMAs/frag-pair).
// 128x256 tile, 8 waves (2Mx4N), wave tile 64x64, BK=32.
// Triple-buffered LDS (3 x 48KB), counted vmcnt(6) pipeline, raw s_barrier,
// XOR-swizzled LDS (pre-swizzled global source per rule #21), XCD-chunked swizzle.
template <int ACT>
__global__ __launch_bounds__(512, 1) void gemm_split2(
    const unsigned short* __restrict__ Ah, const unsigned short* __restrict__ Al,
    const unsigned short* __restrict__ Wh, const unsigned short* __restrict__ Wl,
    const float* __restrict__ bias,
    unsigned short* __restrict__ Ch, unsigned short* __restrict__ Cl) {
  constexpr int K = 512, NN = 512, BM = 128, BN = 256, BK = 32;
  constexpr int NT = K / BK;   // 16 K-tiles
  constexpr int BUF = 24576;   // elements per 48KB buffer (Ah 4096 | Al 4096 | Bh 8192 | Bl 8192)
  extern __shared__ unsigned short lds[];
  const int t = threadIdx.x, l = t & 63, w = t >> 6;
  const int wr = w >> 2, wc = w & 3;

  // bijective XCD-chunked swizzle; nwg = 2048, divisible by 8
  const int bid = blockIdx.x;
  const int wg = (bid & 7) * 256 + (bid >> 3);
  const int br = wg >> 1, bc = wg & 1;  // consecutive wg share the A panel
  const long rowA0 = (long)br * BM;
  const int colB0 = bc * BN;

  // --- staging: 6 x 16B chunks per thread per K-tile, source pre-swizzled ---
  const int rA = t >> 2;                       // A row 0..127
  const int sA = (t & 3) ^ ((rA >> 2) & 3);    // swizzled source k-slot
  const unsigned short* pAh = Ah + (rowA0 + rA) * K + sA * 8;
  const unsigned short* pAl = Al + (rowA0 + rA) * K + sA * 8;
  const int rB0 = t >> 2, rB1 = rB0 + 128;     // B rows 0..127 / 128..255
  const int sB0 = (t & 3) ^ ((rB0 >> 2) & 3);
  const int sB1 = (t & 3) ^ ((rB1 >> 2) & 3);
  const unsigned short* pBh0 = Wh + (long)(colB0 + rB0) * K + sB0 * 8;
  const unsigned short* pBh1 = Wh + (long)(colB0 + rB1) * K + sB1 * 8;
  const unsigned short* pBl0 = Wl + (long)(colB0 + rB0) * K + sB0 * 8;
  const unsigned short* pBl1 = Wl + (long)(colB0 + rB1) * K + sB1 * 8;
  const int wbase = w * 512;  // wave-uniform LDS chunk base (64 lanes * 8 elems)

#define STAGE(bufidx, kofs)                                   \
  {                                                           \
    unsigned short* bq = lds + (bufidx) * BUF;                \
    gl_lds16(pAh + (kofs), bq + wbase);                       \
    gl_lds16(pAl + (kofs), bq + 4096 + wbase);                \
    gl_lds16(pBh0 + (kofs), bq + 8192 + wbase);               \
    gl_lds16(pBh1 + (kofs), bq + 8192 + 4096 + wbase);        \
    gl_lds16(pBl0 + (kofs), bq + 16384 + wbase);              \
    gl_lds16(pBl1 + (kofs), bq + 16384 + 4096 + wbase);       \
  }

  // --- fragment read bases; swizzle term is lane-only (row base is mult of 16) ---
  const int swz = ((l >> 4) ^ ((l >> 2) & 3)) * 8;
  const int baseA = (wr * 64 + (l & 15)) * BK + swz;
  const int baseB = (wc * 64 + (l & 15)) * BK + swz;

  f32x4 acc[4][4] = {};

  STAGE(0, 0);
  STAGE(1, BK);

  for (int tt = 0; tt < NT; ++tt) {
    const int cur = tt % 3;
    // gate: everything older than the most recent 6 loads (tile tt+1) has landed
    if (tt < NT - 1) {
      asm volatile("s_waitcnt vmcnt(6)" ::: "memory");
    } else {
      asm volatile("s_waitcnt vmcnt(0)" ::: "memory");
    }
    __builtin_amdgcn_s_barrier();
    __builtin_amdgcn_sched_barrier(0);
    // stage tile tt+2 into buf[(tt+2)%3]; safe: all waves finished reading that
    // buffer (as tile tt-1) before entering the barrier above
    if (tt + 2 < NT) STAGE((tt + 2) % 3, (tt + 2) * BK);

    const unsigned short* bufc = lds + cur * BUF;
    bf16x8 fah[4], fal[4], fbh[4], fbl[4];
#pragma unroll
    for (int m = 0; m < 4; m++) {
      fah[m] = *(const bf16x8*)(bufc + baseA + m * 512);
      fal[m] = *(const bf16x8*)(bufc + 4096 + baseA + m * 512);
    }
#pragma unroll
    for (int n = 0; n < 4; n++) {
      fbh[n] = *(const bf16x8*)(bufc + 8192 + baseB + n * 512);
      fbl[n] = *(const bf16x8*)(bufc + 16384 + baseB + n * 512);
    }
    __builtin_amdgcn_s_setprio(1);
#pragma unroll
    for (int m = 0; m < 4; m++)
#pragma unroll
      for (int n = 0; n < 4; n++) {
        acc[m][n] = __builtin_amdgcn_mfma_f32_16x16x32_bf16(fah[m], fbh[n], acc[m][n], 0, 0, 0);
        acc[m][n] = __builtin_amdgcn_mfma_f32_16x16x32_bf16(fal[m], fbh[n], acc[m][n], 0, 0, 0);
        acc[m][n] = __builtin_amdgcn_mfma_f32_16x16x32_bf16(fah[m], fbl[n], acc[m][n], 0, 0, 0);
      }
    __builtin_amdgcn_s_setprio(0);
    __builtin_amdgcn_sched_barrier(0);
  }
#undef STAGE

#pragma unroll
  for (int m = 0; m < 4; m++) {
    const long row = rowA0 + wr * 64 + m * 16 + (l >> 4) * 4;
#pragma unroll
    for (int n = 0; n < 4; n++) {
      const int col = colB0 + wc * 64 + n * 16 + (l & 15);
      const float bv = bias[col];
#pragma unroll
      for (int r = 0; r < 4; r++) {
        float x = acc[m][n][r] + bv;
        if (ACT) x = fmaxf(x, 0.0f);
        const unsigned short h = f2bf_rne(x);
        const long idx = (row + r) * NN + col;
        Ch[idx] = h;
        Cl[idx] = f2bf_rne(x - bf2f(h));
      }
    }
  }
}

// dots[b,64,1024] = scale * slots[64,512] @ k[b,1024,512]^T  (split bf16 MFMA, f32 out)
__global__ __launch_bounds__(256) void gemm_dots_split(
    const unsigned short* __restrict__ Qh, const unsigned short* __restrict__ Ql,
    const unsigned short* __restrict__ Kh, const unsigned short* __restrict__ Kl,
    float* __restrict__ dots) {
  constexpr int K = 512, BM = 64, BN = 128, BK = 32;
  __shared__ __align__(16) unsigned short lah[BM * BK];
  __shared__ __align__(16) unsigned short lal[BM * BK];
  __shared__ __align__(16) unsigned short lbh[BN * BK];
  __shared__ __align__(16) unsigned short lbl[BN * BK];
  const int t = threadIdx.x, l = t & 63, w = t >> 6;
  const int b = blockIdx.x >> 3, bc = blockIdx.x & 7;
  const unsigned short* kh = Kh + (long)b * Nn * Dd;
  const unsigned short* kl = Kl + (long)b * Nn * Dd;
  f32x4 acc[4][2] = {};

  for (int k0 = 0; k0 < K; k0 += BK) {
    {
      const int c = t;
      const int ga = (c >> 2) * K + k0 + (c & 3) * 8;
      const int lo = (w * 64) * 8;
      gl_lds16(Qh + ga, lah + lo);
      gl_lds16(Ql + ga, lal + lo);
    }
#pragma unroll
    for (int q = 0; q < 2; q++) {
      const int c = q * 256 + t;
      const long gb = (long)(bc * BN + (c >> 2)) * K + k0 + (c & 3) * 8;
      const int lo = (q * 256 + w * 64) * 8;
      gl_lds16(kh + gb, lbh + lo);
      gl_lds16(kl + gb, lbl + lo);
    }
    __syncthreads();
    bf16x8 ah[4], al[4], bh[2], bl[2];
#pragma unroll
    for (int m = 0; m < 4; m++) {
      const int off = (m * 16 + (l & 15)) * BK + (l >> 4) * 8;
      ah[m] = *(const bf16x8*)(lah + off);
      al[m] = *(const bf16x8*)(lal + off);
    }
#pragma unroll
    for (int n = 0; n < 2; n++) {
      const int off = (w * 32 + n * 16 + (l & 15)) * BK + (l >> 4) * 8;
      bh[n] = *(const bf16x8*)(lbh + off);
      bl[n] = *(const bf16x8*)(lbl + off);
    }
#pragma unroll
    for (int m = 0; m < 4; m++)
#pragma unroll
      for (int n = 0; n < 2; n++) {
        acc[m][n] = __builtin_amdgcn_mfma_f32_16x16x32_bf16(ah[m], bh[n], acc[m][n], 0, 0, 0);
        acc[m][n] = __builtin_amdgcn_mfma_f32_16x16x32_bf16(al[m], bh[n], acc[m][n], 0, 0, 0);
        acc[m][n] = __builtin_amdgcn_mfma_f32_16x16x32_bf16(ah[m], bl[n], acc[m][n], 0, 0, 0);
      }
    __syncthreads();
  }
  float* dp = dots + (long)b * Ss * Nn;
#pragma unroll
  for (int m = 0; m < 4; m++) {
    const int row = m * 16 + (l >> 4) * 4;
#pragma unroll
    for (int n = 0; n < 2; n++) {
      const int col = bc * BN + w * 32 + n * 16 + (l & 15);
#pragma unroll
      for (int r = 0; r < 4; r++) dp[(long)(row + r) * Nn + col] = acc[m][n][r] * kScale;
    }
  }
}

// per-batch: s_j[b,i] = sum_j dots, s_all[b] = sum_ij dots
__global__ __launch_bounds__(256) void reduce_k(
    const float* __restrict__ dots, float* __restrict__ s_j, float* __restrict__ s_all) {
  const int b = blockIdx.x;
  const int t = threadIdx.x;
  const float* dp = dots + (long)b * Ss * Nn;
  const int i = t >> 2, q = t & 3;
  float s = 0.f;
  const float* rp = dp + i * Nn + q * 256;
  for (int j = 0; j < 256; j++) s += rp[j];
  __shared__ float part[256];
  __shared__ float rowsum[64];
  part[t] = s;
  __syncthreads();
  if (t < 64) {
    const float v = part[t * 4] + part[t * 4 + 1] + part[t * 4 + 2] + part[t * 4 + 3];
    rowsum[t] = v;
    s_j[b * 64 + t] = v;
  }
  __syncthreads();
  if (t == 0) {
    float tot = 0.f;
    for (int k = 0; k < 64; k++) tot += rowsum[k];
    s_all[b] = tot;
  }
}

// attn = sigmoid(dots * s_all/s_j) -> out; inv_r = 1/(rowsum(attn)+eps)
__global__ __launch_bounds__(256) void attn_k(
    const float* __restrict__ dots, const float* __restrict__ s_j,
    const float* __restrict__ s_all, float* __restrict__ attn_out,
    float* __restrict__ inv_r) {
  const int bi = blockIdx.x;
  const int b = bi >> 6;
  const int t = threadIdx.x;
  const float ratio = s_all[b] / s_j[bi];
  const float* dp = dots + (long)bi * Nn;
  float* ap = attn_out + (long)bi * Nn;
  float s = 0.f;
#pragma unroll
  for (int q = 0; q < 4; q++) {
    const int j = q * 256 + t;
    const float x = dp[j] * ratio;
    const float a = 1.f / (1.f + expf(-x));
    ap[j] = a;
    s += a;
  }
  __shared__ float red[256];
  red[t] = s;
  __syncthreads();
  for (int off = 128; off > 0; off >>= 1) {
    if (t < off) red[t] += red[t + off];
    __syncthreads();
  }
  if (t == 0) inv_r[bi] = 1.f / (red[0] + kEps);
}

// updates[b,i,d] = inv_r[b,i] * sum_j attn[b,i,j] * inputs[b,j,d]   (fp32, LDS-tiled)
__global__ __launch_bounds__(256) void updates_k(
    const float* __restrict__ attn, const float* __restrict__ inputs,
    const float* __restrict__ inv_r, float* __restrict__ out0) {
  const int b = blockIdx.x >> 2;
  const int dt = blockIdx.x & 3;
  const int t = threadIdx.x;
  __shared__ float att_lds[64 * 32];
  __shared__ float in_lds[32 * 128];
  const int c = (t & 63) * 2;
  const int g = t >> 6;
  float accx[16], accy[16];
#pragma unroll
  for (int i = 0; i < 16; i++) { accx[i] = 0.f; accy[i] = 0.f; }
  for (int j0 = 0; j0 < Nn; j0 += 32) {
    __syncthreads();
#pragma unroll
    for (int s2 = 0; s2 < 8; s2++) {
      const int e = s2 * 256 + t;
      att_lds[e] = attn[(long)(b * 64 + (e >> 5)) * Nn + j0 + (e & 31)];
    }
#pragma unroll
    for (int s2 = 0; s2 < 16; s2++) {
      const int e = s2 * 256 + t;
      in_lds[e] = inputs[(long)b * Nn * Dd + (long)(j0 + (e >> 7)) * Dd + dt * 128 + (e & 127)];
    }
    __syncthreads();
#pragma unroll 4
    for (int jj = 0; jj < 32; jj++) {
      const float ix = in_lds[jj * 128 + c];
      const float iy = in_lds[jj * 128 + c + 1];
#pragma unroll
      for (int ii = 0; ii < 16; ii++) {
        const float a = att_lds[(g * 16 + ii) * 32 + jj];
        accx[ii] += a * ix;
        accy[ii] += a * iy;
      }
    }
  }
#pragma unroll
  for (int ii = 0; ii < 16; ii++) {
    const int i = g * 16 + ii;
    const float ir = inv_r[b * 64 + i];
    const long o = (long)(b * 64 + i) * Dd + dt * 128 + c;
    out0[o] = accx[ii] * ir;
    out0[o + 1] = accy[ii] * ir;
  }
}

extern "C" void kernel_launch(void* const* d_in, const int* in_sizes, int n_in,
                              void* d_out, int out_size, void* d_ws, size_t ws_size,
                              hipStream_t stream) {
  (void)in_sizes; (void)n_in; (void)out_size; (void)ws_size;
  const float* inputs_pe = (const float*)d_in[0];
  const float* inputs = (const float*)d_in[1];
  const float* slots = (const float*)d_in[2];
  const float* W1 = (const float*)d_in[3];
  const float* b1 = (const float*)d_in[4];
  const float* W2 = (const float*)d_in[5];
  const float* b2 = (const float*)d_in[6];
  const float* W3 = (const float*)d_in[7];
  const float* b3 = (const float*)d_in[8];

  char* ws = (char*)d_ws;
  size_t off = 0;
  auto alloc = [&](size_t bytes) -> void* {
    void* p = ws + off;
    off += (bytes + 255) & ~(size_t)255;
    return p;
  };
  const size_t actB = (size_t)Bb * Nn * Dd * 2;
  unsigned short* Ahi = (unsigned short*)alloc(actB);
  unsigned short* Alo = (unsigned short*)alloc(actB);
  unsigned short* Bhi = (unsigned short*)alloc(actB);
  unsigned short* Blo = (unsigned short*)alloc(actB);
  unsigned short* w1h = (unsigned short*)alloc(Dd * Dd * 2);
  unsigned short* w1l = (unsigned short*)alloc(Dd * Dd * 2);
  unsigned short* w2h = (unsigned short*)alloc(Dd * Dd * 2);
  unsigned short* w2l = (unsigned short*)alloc(Dd * Dd * 2);
  unsigned short* w3h = (unsigned short*)alloc(Dd * Dd * 2);
  unsigned short* w3l = (unsigned short*)alloc(Dd * Dd * 2);
  unsigned short* sh = (unsigned short*)alloc(Ss * Dd * 2);
  unsigned short* sl = (unsigned short*)alloc(Ss * Dd * 2);
  float* dotsb = (float*)alloc((size_t)Bb * Ss * Nn * 4);
  float* s_j = (float*)alloc(Bb * Ss * 4);
  float* s_all = (float*)alloc(Bb * 4);
  float* inv_r = (float*)alloc(Bb * Ss * 4);

  float* out_updates = (float*)d_out;
  float* out_attn = out_updates + (size_t)Bb * Ss * Dd;

  const int kLds = 3 * 48 * 1024;  // 144KB dynamic LDS (<=160KB with opt-in)
  hipFuncSetAttribute(reinterpret_cast<const void*>(gemm_split2<1>),
                      hipFuncAttributeMaxDynamicSharedMemorySize, kLds);
  hipFuncSetAttribute(reinterpret_cast<const void*>(gemm_split2<0>),
                      hipFuncAttributeMaxDynamicSharedMemorySize, kLds);

  cast_split<<<4096, 256, 0, stream>>>(inputs_pe, Ahi, Alo, Bb * Nn * Dd / 4);
  cast_split<<<256, 256, 0, stream>>>(W1, w1h, w1l, Dd * Dd / 4);
  cast_split<<<256, 256, 0, stream>>>(W2, w2h, w2l, Dd * Dd / 4);
  cast_split<<<256, 256, 0, stream>>>(W3, w3h, w3l, Dd * Dd / 4);
  cast_split<<<32, 256, 0, stream>>>(slots, sh, sl, Ss * Dd / 4);

  gemm_split2<1><<<2048, 512, kLds, stream>>>(Ahi, Alo, w1h, w1l, b1, Bhi, Blo);
  gemm_split2<1><<<2048, 512, kLds, stream>>>(Bhi, Blo, w2h, w2l, b2, Ahi, Alo);
  gemm_split2<0><<<2048, 512, kLds, stream>>>(Ahi, Alo, w3h, w3l, b3, Bhi, Blo);

  gemm_dots_split<<<Bb * 8, 256, 0, stream>>>(sh, sl, Bhi, Blo, dotsb);
  reduce_k<<<Bb, 256, 0, stream>>>(dotsb, s_j, s_all);
  attn_k<<<Bb * Ss, 256, 0, stream>>>(dotsb, s_j, s_all, out_attn, inv_r);
  updates_k<<<Bb * 4, 256, 0, stream>>>(out_attn, inputs, inv_r, out_updates);
}

// Round 3
// 1165.634 us; speedup vs baseline: 1.1321x; 1.0345x over previous
//
#include <hip/hip_runtime.h>
#include <stdint.h>

#define Bb 128
#define Nn 1024
#define Dd 512
#define Ss 64

constexpr float kScale = 0.044194173824159216f;  // 512^-0.5
constexpr float kEps = 1e-8f;

typedef __bf16 bf16x8 __attribute__((ext_vector_type(8)));
typedef float f32x4 __attribute__((ext_vector_type(4)));
typedef float f32x16 __attribute__((ext_vector_type(16)));

__device__ inline unsigned short f2bf_rne(float x) {
  unsigned u = __builtin_bit_cast(unsigned, x);
  u += 0x7FFFu + ((u >> 16) & 1u);
  return (unsigned short)(u >> 16);
}
__device__ inline float bf2f(unsigned short h) {
  unsigned u = ((unsigned)h) << 16;
  return __builtin_bit_cast(float, u);
}

// async global->LDS, 16B per lane; LDS dest must be wave-uniform base (HW adds lane*16)
__device__ inline void gl_lds16(const void* g, void* l) {
  typedef unsigned int u32;
  auto gp = (u32 __attribute__((address_space(1)))*)(unsigned long long)(uintptr_t)g;
  auto lp = (u32 __attribute__((address_space(3)))*)(unsigned int)(uintptr_t)l;
  __builtin_amdgcn_global_load_lds(gp, lp, 16, 0, 0);
}

// f32 -> bf16 hi/lo split (a ~= hi + lo, residual ~2^-16 rel)
__global__ void cast_split(const float* __restrict__ in,
                           unsigned short* __restrict__ hi,
                           unsigned short* __restrict__ lo,
                           int n4) {
  int i = blockIdx.x * blockDim.x + threadIdx.x;
  const int stride = gridDim.x * blockDim.x;
  for (; i < n4; i += stride) {
    const float4 v = ((const float4*)in)[i];
    ushort4 h, lw;
    h.x = f2bf_rne(v.x); lw.x = f2bf_rne(v.x - bf2f(h.x));
    h.y = f2bf_rne(v.y); lw.y = f2bf_rne(v.y - bf2f(h.y));
    h.z = f2bf_rne(v.z); lw.z = f2bf_rne(v.z - bf2f(h.z));
    h.w = f2bf_rne(v.w); lw.w = f2bf_rne(v.w - bf2f(h.w));
    ((ushort4*)hi)[i] = h;
    ((ushort4*)lo)[i] = lw;
  }
}

// C[M,512] = act(A[M,512] @ W[512,512]^T + bias), split bf16 (3 MFMAs per pair).
// Full-width: block = 128 rows x 512 cols -> A read exactly once from HBM.
// 8 waves (2x4), wave-tile 64x128, BK=16, v_mfma_f32_32x32x16_bf16.
// LDS buffer 40KB = Ah[128][16] | Al | Wh[512][16] | Wl ([row][16] subtiles ->
// conflict-free b128 frag reads). Triple-buffered, counted vmcnt(5) pipeline.
template <int ACT>
__global__ __launch_bounds__(512, 1) void gemm_full(
    const unsigned short* __restrict__ Ah, const unsigned short* __restrict__ Al,
    const unsigned short* __restrict__ Wh, const unsigned short* __restrict__ Wl,
    const float* __restrict__ bias,
    unsigned short* __restrict__ Ch, unsigned short* __restrict__ Cl) {
  constexpr int K = 512, BK = 16;
  constexpr int NT = K / BK;   // 32 K-tiles
  constexpr int BUF = 20480;   // ushorts per 40KB buffer: Ah@0 Al@2048 Wh@4096 Wl@12288
  extern __shared__ unsigned short lds[];
  const int t = threadIdx.x, l = t & 63, w = t >> 6;
  const int wr = w >> 2, wc = w & 3;
  const long rowA0 = (long)blockIdx.x * 128;

  // staging sources (per-lane): 1 A-chunk + 4 W-chunks per thread per K-tile
  const int p = w >> 2, q = w & 3;  // A: part (hi/lo), quarter (32 rows)
  const unsigned short* srcA = (p ? Al : Ah) + (rowA0 + q * 32 + (l >> 1)) * K + (l & 1) * 8;
  const int s0 = w * 2, s1 = w * 2 + 1;  // W: 16 segments of 32 rows
  const unsigned short* srcWh0 = Wh + (long)(s0 * 32 + (l >> 1)) * K + (l & 1) * 8;
  const unsigned short* srcWh1 = Wh + (long)(s1 * 32 + (l >> 1)) * K + (l & 1) * 8;
  const unsigned short* srcWl0 = Wl + (long)(s0 * 32 + (l >> 1)) * K + (l & 1) * 8;
  const unsigned short* srcWl1 = Wl + (long)(s1 * 32 + (l >> 1)) * K + (l & 1) * 8;
  const int dA = p * 2048 + q * 512;  // wave-uniform LDS dests (ushort units)

#define GSTAGE(bufi, koff)                                    \
  {                                                           \
    unsigned short* bq = lds + (bufi)*BUF;                    \
    gl_lds16(srcA + (koff), bq + dA);                         \
    gl_lds16(srcWh0 + (koff), bq + 4096 + s0 * 512);          \
    gl_lds16(srcWh1 + (koff), bq + 4096 + s1 * 512);          \
    gl_lds16(srcWl0 + (koff), bq + 12288 + s0 * 512);         \
    gl_lds16(srcWl1 + (koff), bq + 12288 + s1 * 512);         \
  }

  // frag addresses: [row][16] layout; granule = row*2 + (l>>5): 64 distinct -> no conflicts
  const int fra = (l & 31) * 16 + (l >> 5) * 8;

  f32x16 acc[2][4] = {};

  GSTAGE(0, 0);
  GSTAGE(1, BK);

  for (int tt = 0; tt < NT; ++tt) {
    if (tt < NT - 1) {
      asm volatile("s_waitcnt vmcnt(5)" ::: "memory");
    } else {
      asm volatile("s_waitcnt vmcnt(0)" ::: "memory");
    }
    __builtin_amdgcn_s_barrier();
    __builtin_amdgcn_sched_barrier(0);
    if (tt < NT - 2) GSTAGE((tt + 2) % 3, (tt + 2) * BK);

    const unsigned short* bufc = lds + (tt % 3) * BUF;
    bf16x8 fah[2], fal[2], fbh[4], fbl[4];
#pragma unroll
    for (int m = 0; m < 2; m++) {
      fah[m] = *(const bf16x8*)(bufc + wr * 1024 + m * 512 + fra);
      fal[m] = *(const bf16x8*)(bufc + 2048 + wr * 1024 + m * 512 + fra);
    }
#pragma unroll
    for (int n = 0; n < 4; n++) {
      fbh[n] = *(const bf16x8*)(bufc + 4096 + wc * 2048 + n * 512 + fra);
      fbl[n] = *(const bf16x8*)(bufc + 12288 + wc * 2048 + n * 512 + fra);
    }
    __builtin_amdgcn_s_setprio(1);
#pragma unroll
    for (int m = 0; m < 2; m++)
#pragma unroll
      for (int n = 0; n < 4; n++) {
        acc[m][n] = __builtin_amdgcn_mfma_f32_32x32x16_bf16(fah[m], fbh[n], acc[m][n], 0, 0, 0);
        acc[m][n] = __builtin_amdgcn_mfma_f32_32x32x16_bf16(fal[m], fbh[n], acc[m][n], 0, 0, 0);
        acc[m][n] = __builtin_amdgcn_mfma_f32_32x32x16_bf16(fah[m], fbl[n], acc[m][n], 0, 0, 0);
      }
    __builtin_amdgcn_s_setprio(0);
    __builtin_amdgcn_sched_barrier(0);
  }
#undef GSTAGE

  // C/D 32x32: col = l&31, row = (r&3) + 8*(r>>2) + 4*(l>>5)
#pragma unroll
  for (int m = 0; m < 2; m++)
#pragma unroll
    for (int n = 0; n < 4; n++) {
      const int col = wc * 128 + n * 32 + (l & 31);
      const float bv = bias[col];
#pragma unroll
      for (int r = 0; r < 16; r++) {
        const long row = rowA0 + wr * 64 + m * 32 + (r & 3) + 8 * (r >> 2) + 4 * (l >> 5);
        float x = acc[m][n][r] + bv;
        if (ACT) x = fmaxf(x, 0.0f);
        const unsigned short h = f2bf_rne(x);
        const long idx = row * 512 + col;
        Ch[idx] = h;
        Cl[idx] = f2bf_rne(x - bf2f(h));
      }
    }
}

// dots[b,64,1024] = scale * slots[64,512] @ k[b,1024,512]^T  (split bf16 MFMA, f32 out)
__global__ __launch_bounds__(256) void gemm_dots_split(
    const unsigned short* __restrict__ Qh, const unsigned short* __restrict__ Ql,
    const unsigned short* __restrict__ Kh, const unsigned short* __restrict__ Kl,
    float* __restrict__ dots) {
  constexpr int K = 512, BM = 64, BN = 128, BK = 32;
  __shared__ __align__(16) unsigned short lah[BM * BK];
  __shared__ __align__(16) unsigned short lal[BM * BK];
  __shared__ __align__(16) unsigned short lbh[BN * BK];
  __shared__ __align__(16) unsigned short lbl[BN * BK];
  const int t = threadIdx.x, l = t & 63, w = t >> 6;
  const int b = blockIdx.x >> 3, bc = blockIdx.x & 7;
  const unsigned short* kh = Kh + (long)b * Nn * Dd;
  const unsigned short* kl = Kl + (long)b * Nn * Dd;
  f32x4 acc[4][2] = {};

  for (int k0 = 0; k0 < K; k0 += BK) {
    {
      const int c = t;
      const int ga = (c >> 2) * K + k0 + (c & 3) * 8;
      const int lo = (w * 64) * 8;
      gl_lds16(Qh + ga, lah + lo);
      gl_lds16(Ql + ga, lal + lo);
    }
#pragma unroll
    for (int qq = 0; qq < 2; qq++) {
      const int c = qq * 256 + t;
      const long gb = (long)(bc * BN + (c >> 2)) * K + k0 + (c & 3) * 8;
      const int lo = (qq * 256 + w * 64) * 8;
      gl_lds16(kh + gb, lbh + lo);
      gl_lds16(kl + gb, lbl + lo);
    }
    __syncthreads();
    bf16x8 ah[4], al[4], bh[2], bl[2];
#pragma unroll
    for (int m = 0; m < 4; m++) {
      const int off = (m * 16 + (l & 15)) * BK + (l >> 4) * 8;
      ah[m] = *(const bf16x8*)(lah + off);
      al[m] = *(const bf16x8*)(lal + off);
    }
#pragma unroll
    for (int n = 0; n < 2; n++) {
      const int off = (w * 32 + n * 16 + (l & 15)) * BK + (l >> 4) * 8;
      bh[n] = *(const bf16x8*)(lbh + off);
      bl[n] = *(const bf16x8*)(lbl + off);
    }
#pragma unroll
    for (int m = 0; m < 4; m++)
#pragma unroll
      for (int n = 0; n < 2; n++) {
        acc[m][n] = __builtin_amdgcn_mfma_f32_16x16x32_bf16(ah[m], bh[n], acc[m][n], 0, 0, 0);
        acc[m][n] = __builtin_amdgcn_mfma_f32_16x16x32_bf16(al[m], bh[n], acc[m][n], 0, 0, 0);
        acc[m][n] = __builtin_amdgcn_mfma_f32_16x16x32_bf16(ah[m], bl[n], acc[m][n], 0, 0, 0);
      }
    __syncthreads();
  }
  float* dp = dots + (long)b * Ss * Nn;
#pragma unroll
  for (int m = 0; m < 4; m++) {
    const int row = m * 16 + (l >> 4) * 4;
#pragma unroll
    for (int n = 0; n < 2; n++) {
      const int col = bc * BN + w * 32 + n * 16 + (l & 15);
#pragma unroll
      for (int r = 0; r < 4; r++) dp[(long)(row + r) * Nn + col] = acc[m][n][r] * kScale;
    }
  }
}

// per-batch: s_j[b,i] = sum_j dots, s_all[b] = sum_ij dots
__global__ __launch_bounds__(256) void reduce_k(
    const float* __restrict__ dots, float* __restrict__ s_j, float* __restrict__ s_all) {
  const int b = blockIdx.x;
  const int t = threadIdx.x;
  const float* dp = dots + (long)b * Ss * Nn;
  const int i = t >> 2, qq = t & 3;
  float s = 0.f;
  const float* rp = dp + i * Nn + qq * 256;
  for (int j = 0; j < 256; j++) s += rp[j];
  __shared__ float part[256];
  __shared__ float rowsum[64];
  part[t] = s;
  __syncthreads();
  if (t < 64) {
    const float v = part[t * 4] + part[t * 4 + 1] + part[t * 4 + 2] + part[t * 4 + 3];
    rowsum[t] = v;
    s_j[b * 64 + t] = v;
  }
  __syncthreads();
  if (t == 0) {
    float tot = 0.f;
    for (int k = 0; k < 64; k++) tot += rowsum[k];
    s_all[b] = tot;
  }
}

// attn = sigmoid(dots * s_all/s_j) -> out; inv_r = 1/(rowsum(attn)+eps)
__global__ __launch_bounds__(256) void attn_k(
    const float* __restrict__ dots, const float* __restrict__ s_j,
    const float* __restrict__ s_all, float* __restrict__ attn_out,
    float* __restrict__ inv_r) {
  const int bi = blockIdx.x;
  const int b = bi >> 6;
  const int t = threadIdx.x;
  const float ratio = s_all[b] / s_j[bi];
  const float* dp = dots + (long)bi * Nn;
  float* ap = attn_out + (long)bi * Nn;
  float s = 0.f;
#pragma unroll
  for (int qq = 0; qq < 4; qq++) {
    const int j = qq * 256 + t;
    const float x = dp[j] * ratio;
    const float a = 1.f / (1.f + expf(-x));
    ap[j] = a;
    s += a;
  }
  __shared__ float red[256];
  red[t] = s;
  __syncthreads();
  for (int off = 128; off > 0; off >>= 1) {
    if (t < off) red[t] += red[t + off];
    __syncthreads();
  }
  if (t == 0) inv_r[bi] = 1.f / (red[0] + kEps);
}

// updates[b,i,d] = inv_r[b,i] * sum_j attn[b,i,j] * inputs[b,j,d]  (fp32 register tile)
// block = (b, dt): 64 i x 256 d; 256 threads; thread tile 8i x 8d (64 FMA / 4 b128 LDS reads).
// LDS buffer 40KB = in[32][256] f32 (gl_lds16-staged) | attT[32][64] f32 (reg-staged,
// transposed -> broadcast reads). Triple-buffered, counted-vmcnt pipeline.
__global__ __launch_bounds__(256, 1) void updates_k2(
    const float* __restrict__ attn, const float* __restrict__ inputs,
    const float* __restrict__ inv_r, float* __restrict__ out0) {
  constexpr int NT2 = 32;       // 1024 / 32
  constexpr int BUF_F = 10240;  // floats per 40KB buffer: in@0 (8192), attT@8192 (2048)
  extern __shared__ float ldsf[];
  const int t = threadIdx.x, lam = t & 63, w = t >> 6;
  const int b = blockIdx.x >> 1, dt = blockIdx.x & 1;
  const int ig = t >> 5, dg = t & 31;
  const float* inb = inputs + (size_t)b * (Nn * Dd) + dt * 256;
  const float* attsrc = attn + (size_t)b * (Ss * Nn) + (size_t)(t >> 2) * Nn + (t & 3) * 8;
  float acc[8][8] = {};
  float4 ga0, ga1, gb0, gb1;

#define UISSUE(bufi, tile, G0, G1)                                        \
  {                                                                       \
    const int j0_ = (tile)*32;                                            \
    G0 = *(const float4*)(attsrc + j0_);                                  \
    G1 = *(const float4*)(attsrc + j0_ + 4);                              \
    float* db_ = ldsf + (bufi)*BUF_F;                                     \
    _Pragma("unroll") for (int i_ = 0; i_ < 8; i_++) {                    \
      const int row_ = i_ * 4 + w;                                        \
      gl_lds16(inb + (size_t)(j0_ + row_) * Dd + lam * 4, db_ + row_ * 256); \
    }                                                                     \
  }

#define UWRITE(bufi, G0, G1)                                              \
  {                                                                       \
    float* ab_ = ldsf + (bufi)*BUF_F + 8192;                              \
    const int col_ = t >> 2;                                              \
    const int r0_ = (t & 3) * 8;                                          \
    ab_[(r0_ + 0) * 64 + col_] = G0.x;                                    \
    ab_[(r0_ + 1) * 64 + col_] = G0.y;                                    \
    ab_[(r0_ + 2) * 64 + col_] = G0.z;                                    \
    ab_[(r0_ + 3) * 64 + col_] = G0.w;                                    \
    ab_[(r0_ + 4) * 64 + col_] = G1.x;                                    \
    ab_[(r0_ + 5) * 64 + col_] = G1.y;                                    \
    ab_[(r0_ + 6) * 64 + col_] = G1.z;                                    \
    ab_[(r0_ + 7) * 64 + col_] = G1.w;                                    \
  }

#define UCOMP(bufi)                                                       \
  {                                                                       \
    const float* db_ = ldsf + (bufi)*BUF_F;                               \
    const float* ab_ = db_ + 8192;                                        \
    _Pragma("unroll 4") for (int jj = 0; jj < 32; jj++) {                 \
      float av[8], vv[8];                                                 \
      *(float4*)&av[0] = *(const float4*)(ab_ + jj * 64 + ig * 8);        \
      *(float4*)&av[4] = *(const float4*)(ab_ + jj * 64 + ig * 8 + 4);    \
      *(float4*)&vv[0] = *(const float4*)(db_ + jj * 256 + dg * 8);       \
      *(float4*)&vv[4] = *(const float4*)(db_ + jj * 256 + dg * 8 + 4);   \
      _Pragma("unroll") for (int m_ = 0; m_ < 8; m_++)                    \
          _Pragma("unroll") for (int n_ = 0; n_ < 8; n_++)                \
              acc[m_][n_] = __builtin_fmaf(av[m_], vv[n_], acc[m_][n_]);  \
    }                                                                     \
  }

  UISSUE(0, 0, ga0, ga1);
  UISSUE(1, 1, gb0, gb1);
  UWRITE(0, ga0, ga1);  // compiler auto-waits the ga regs

  for (int tt = 0; tt < NT2; tt += 2) {
    // ---- even iter tt: write tile tt+1 (set B), issue tile tt+2 (set A) ----
    asm volatile("s_waitcnt vmcnt(10)" ::: "memory");  // tile tt fully in LDS
    UWRITE((tt + 1) % 3, gb0, gb1);
    asm volatile("s_waitcnt lgkmcnt(0)" ::: "memory");
    __builtin_amdgcn_s_barrier();
    __builtin_amdgcn_sched_barrier(0);
    if (tt < NT2 - 2) UISSUE((tt + 2) % 3, tt + 2, ga0, ga1);
    UCOMP(tt % 3);
    // ---- odd iter tt+1: write tile tt+2 (set A), issue tile tt+3 (set B) ----
    if (tt + 1 < NT2 - 1) {
      asm volatile("s_waitcnt vmcnt(10)" ::: "memory");
    } else {
      asm volatile("s_waitcnt vmcnt(0)" ::: "memory");
    }
    if (tt + 1 < NT2 - 1) UWRITE((tt + 2) % 3, ga0, ga1);
    asm volatile("s_waitcnt lgkmcnt(0)" ::: "memory");
    __builtin_amdgcn_s_barrier();
    __builtin_amdgcn_sched_barrier(0);
    if (tt + 1 < NT2 - 2) UISSUE((tt + 3) % 3, tt + 3, gb0, gb1);
    UCOMP((tt + 1) % 3);
  }
#undef UISSUE
#undef UWRITE
#undef UCOMP

#pragma unroll
  for (int m = 0; m < 8; m++) {
    const int i = ig * 8 + m;
    const float ir = inv_r[b * 64 + i];
    float4 o0, o1;
    o0.x = acc[m][0] * ir; o0.y = acc[m][1] * ir; o0.z = acc[m][2] * ir; o0.w = acc[m][3] * ir;
    o1.x = acc[m][4] * ir; o1.y = acc[m][5] * ir; o1.z = acc[m][6] * ir; o1.w = acc[m][7] * ir;
    float* op = out0 + (size_t)(b * 64 + i) * Dd + dt * 256 + dg * 8;
    *(float4*)op = o0;
    *(float4*)(op + 4) = o1;
  }
}

extern "C" void kernel_launch(void* const* d_in, const int* in_sizes, int n_in,
                              void* d_out, int out_size, void* d_ws, size_t ws_size,
                              hipStream_t stream) {
  (void)in_sizes; (void)n_in; (void)out_size; (void)ws_size;
  const float* inputs_pe = (const float*)d_in[0];
  const float* inputs = (const float*)d_in[1];
  const float* slots = (const float*)d_in[2];
  const float* W1 = (const float*)d_in[3];
  const float* b1 = (const float*)d_in[4];
  const float* W2 = (const float*)d_in[5];
  const float* b2 = (const float*)d_in[6];
  const float* W3 = (const float*)d_in[7];
  const float* b3 = (const float*)d_in[8];

  char* ws = (char*)d_ws;
  size_t off = 0;
  auto alloc = [&](size_t bytes) -> void* {
    void* p = ws + off;
    off += (bytes + 255) & ~(size_t)255;
    return p;
  };
  const size_t actB = (size_t)Bb * Nn * Dd * 2;
  unsigned short* Ahi = (unsigned short*)alloc(actB);
  unsigned short* Alo = (unsigned short*)alloc(actB);
  unsigned short* Bhi = (unsigned short*)alloc(actB);
  unsigned short* Blo = (unsigned short*)alloc(actB);
  unsigned short* w1h = (unsigned short*)alloc(Dd * Dd * 2);
  unsigned short* w1l = (unsigned short*)alloc(Dd * Dd * 2);
  unsigned short* w2h = (unsigned short*)alloc(Dd * Dd * 2);
  unsigned short* w2l = (unsigned short*)alloc(Dd * Dd * 2);
  unsigned short* w3h = (unsigned short*)alloc(Dd * Dd * 2);
  unsigned short* w3l = (unsigned short*)alloc(Dd * Dd * 2);
  unsigned short* sh = (unsigned short*)alloc(Ss * Dd * 2);
  unsigned short* sl = (unsigned short*)alloc(Ss * Dd * 2);
  float* dotsb = (float*)alloc((size_t)Bb * Ss * Nn * 4);
  float* s_j = (float*)alloc(Bb * Ss * 4);
  float* s_all = (float*)alloc(Bb * 4);
  float* inv_r = (float*)alloc(Bb * Ss * 4);

  float* out_updates = (float*)d_out;
  float* out_attn = out_updates + (size_t)Bb * Ss * Dd;

  const int kLds = 3 * 40 * 1024;  // 120KB dynamic LDS
  hipFuncSetAttribute(reinterpret_cast<const void*>(gemm_full<1>),
                      hipFuncAttributeMaxDynamicSharedMemorySize, kLds);
  hipFuncSetAttribute(reinterpret_cast<const void*>(gemm_full<0>),
                      hipFuncAttributeMaxDynamicSharedMemorySize, kLds);
  hipFuncSetAttribute(reinterpret_cast<const void*>(updates_k2),
                      hipFuncAttributeMaxDynamicSharedMemorySize, kLds);

  cast_split<<<4096, 256, 0, stream>>>(inputs_pe, Ahi, Alo, Bb * Nn * Dd / 4);
  cast_split<<<256, 256, 0, stream>>>(W1, w1h, w1l, Dd * Dd / 4);
  cast_split<<<256, 256, 0, stream>>>(W2, w2h, w2l, Dd * Dd / 4);
  cast_split<<<256, 256, 0, stream>>>(W3, w3h, w3l, Dd * Dd / 4);
  cast_split<<<32, 256, 0, stream>>>(slots, sh, sl, Ss * Dd / 4);

  gemm_full<1><<<1024, 512, kLds, stream>>>(Ahi, Alo, w1h, w1l, b1, Bhi, Blo);
  gemm_full<1><<<1024, 512, kLds, stream>>>(Bhi, Blo, w2h, w2l, b2, Ahi, Alo);
  gemm_full<0><<<1024, 512, kLds, stream>>>(Ahi, Alo, w3h, w3l, b3, Bhi, Blo);

  gemm_dots_split<<<Bb * 8, 256, 0, stream>>>(sh, sl, Bhi, Blo, dotsb);
  reduce_k<<<Bb, 256, 0, stream>>>(dotsb, s_j, s_all);
  attn_k<<<Bb * Ss, 256, 0, stream>>>(dotsb, s_j, s_all, out_attn, inv_r);
  updates_k2<<<Bb * 2, 256, kLds, stream>>>(out_attn, inputs, inv_r, out_updates);
}